// Round 7
// baseline (584.691 us; speedup 1.0000x reference)
//
#include <hip/hip_runtime.h>
#include <hip/hip_bf16.h>
#include <math.h>

typedef __attribute__((ext_vector_type(8))) __bf16 bf16x8;
typedef __attribute__((ext_vector_type(4))) __bf16 bf16x4;
typedef __attribute__((ext_vector_type(4))) float f32x4;
typedef __attribute__((ext_vector_type(4))) short short4_t;

#define D_MODEL 1024
#define SEQ     2048
#define BATCH   4
#define NH      16
#define HD      64
#define MROWS   (BATCH * SEQ)   // 8192

// 0.125 (1/sqrt(64)) * log2(e): folded into Q at the QKV-GEMM epilogue
#define SCALE_LOG2E 0.18033688011112042f

__device__ __forceinline__ void gld_lds16(const __bf16* g, __bf16* l) {
  __builtin_amdgcn_global_load_lds(
      (const __attribute__((address_space(1))) void*)g,
      (__attribute__((address_space(3))) void*)l, 16, 0, 0);
}

// ---------------- convert x: fp32 -> bf16, vectorized ----------------
__global__ __launch_bounds__(256) void cvt_x(const float* __restrict__ in,
                                             __bf16* __restrict__ out) {
  int i = (blockIdx.x * 256 + threadIdx.x) * 4;
  float4 f = *(const float4*)(in + i);
  bf16x4 o;
  o.x = (__bf16)f.x; o.y = (__bf16)f.y; o.z = (__bf16)f.z; o.w = (__bf16)f.w;
  *(bf16x4*)(out + i) = o;
}

// ------- convert + transpose weight: fp32 [K][N] -> bf16 [N][K] -------
__global__ __launch_bounds__(256) void cvt_wt(const float* __restrict__ W,
                                              __bf16* __restrict__ Wt) {
  __shared__ __bf16 t[32][33];
  int tx = threadIdx.x, ty = threadIdx.y;   // block (32,8)
  int n0 = blockIdx.x * 32, k0 = blockIdx.y * 32;
#pragma unroll
  for (int j = 0; j < 32; j += 8)
    t[ty + j][tx] = (__bf16)W[(size_t)(k0 + ty + j) * D_MODEL + n0 + tx];
  __syncthreads();
#pragma unroll
  for (int j = 0; j < 32; j += 8)
    Wt[(size_t)(n0 + ty + j) * D_MODEL + k0 + tx] = t[tx][ty + j];
}

// ---------------- GEMM: C[M,N] = A[M,K] @ Bt[N,K]^T  (bf16, m97 structure)
// Operand-swap trick: passing (Bfrag, Afrag) to MFMA yields C^T tiles, so a
// lane holds 4 CONSECUTIVE minor-dim outputs -> vector stores.
// EPI 0 (SWAP): QK, N=2048. lane: token=l16, d=quad*4+i -> bf16x4 to [b,h,n,d]
// EPI 1 (no swap): V, N=1024. lane: d=l16, token=quad*4+i -> bf16x4 to [b,h,d,n]
// EPI 2 (SWAP): proj, N=1024 fp32. lane: row=l16, col=quad*4+i -> float4+bias
template <int EPI>
__global__ __launch_bounds__(256) void gemm_bt(const __bf16* __restrict__ A,
                                               const __bf16* __restrict__ Bt,
                                               const float* __restrict__ bias,
                                               void* __restrict__ Cout) {
  constexpr int Kd = 1024;
  constexpr bool SWAP = (EPI != 1);
  __shared__ __bf16 As[128 * 32];
  __shared__ __bf16 Bs[128 * 32];
  const int tid = threadIdx.x;
  const int lane = tid & 63;
  const int w = tid >> 6;
  const int quad = lane >> 4, l16 = lane & 15;
  const int wr = w >> 1, wc = w & 1;
  const int tm = blockIdx.y * 128, tn = blockIdx.x * 128;

  f32x4 acc[4][4] = {};

  const int u0 = (w * 2) * 64 + lane;
  const int u1 = u0 + 64;
  const int rA0 = u0 >> 2, kofs0 = (u0 & 3) * 8;
  const int rA1 = u1 >> 2, kofs1 = (u1 & 3) * 8;
  const __bf16* gA0 = A + (size_t)(tm + rA0) * Kd + kofs0;
  const __bf16* gA1 = A + (size_t)(tm + rA1) * Kd + kofs1;
  const __bf16* gB0 = Bt + (size_t)(tn + rA0) * Kd + kofs0;
  const __bf16* gB1 = Bt + (size_t)(tn + rA1) * Kd + kofs1;
  __bf16* lA0 = As + (w * 2 + 0) * 512;
  __bf16* lA1 = As + (w * 2 + 1) * 512;
  __bf16* lB0 = Bs + (w * 2 + 0) * 512;
  __bf16* lB1 = Bs + (w * 2 + 1) * 512;

  for (int k0 = 0; k0 < Kd; k0 += 32) {
    gld_lds16(gA0 + k0, lA0);
    gld_lds16(gA1 + k0, lA1);
    gld_lds16(gB0 + k0, lB0);
    gld_lds16(gB1 + k0, lB1);
    __syncthreads();
    bf16x8 af[4], bfr[4];
#pragma unroll
    for (int t = 0; t < 4; ++t) {
      af[t]  = *(const bf16x8*)&As[(wr * 64 + t * 16 + l16) * 32 + quad * 8];
      bfr[t] = *(const bf16x8*)&Bs[(wc * 64 + t * 16 + l16) * 32 + quad * 8];
    }
#pragma unroll
    for (int mt = 0; mt < 4; ++mt)
#pragma unroll
      for (int nt = 0; nt < 4; ++nt) {
        if constexpr (SWAP)
          acc[mt][nt] = __builtin_amdgcn_mfma_f32_16x16x32_bf16(
              bfr[nt], af[mt], acc[mt][nt], 0, 0, 0);
        else
          acc[mt][nt] = __builtin_amdgcn_mfma_f32_16x16x32_bf16(
              af[mt], bfr[nt], acc[mt][nt], 0, 0, 0);
      }
    __syncthreads();
  }

#pragma unroll
  for (int mt = 0; mt < 4; ++mt)
#pragma unroll
    for (int nt = 0; nt < 4; ++nt) {
      if constexpr (EPI == 2) {
        int gm  = tm + wr * 64 + mt * 16 + l16;        // token
        int gn0 = tn + wc * 64 + nt * 16 + quad * 4;   // col base
        float4 bv = *(const float4*)&bias[gn0];
        float4 o;
        o.x = acc[mt][nt][0] + bv.x;
        o.y = acc[mt][nt][1] + bv.y;
        o.z = acc[mt][nt][2] + bv.z;
        o.w = acc[mt][nt][3] + bv.w;
        *(float4*)&((float*)Cout)[(size_t)gm * 1024 + gn0] = o;
      } else if constexpr (EPI == 0) {
        int gm = tm + wr * 64 + mt * 16 + l16;         // token
        int f0 = tn + wc * 64 + nt * 16 + quad * 4;    // 0..2047 (Q|K)
        int which = f0 >> 10, col = f0 & 1023;
        int b = gm >> 11, nn = gm & 2047, h = col >> 6, d = col & 63;
        float s = (which == 0) ? SCALE_LOG2E : 1.0f;
        bf16x4 o;
        o[0] = (__bf16)(acc[mt][nt][0] * s);
        o[1] = (__bf16)(acc[mt][nt][1] * s);
        o[2] = (__bf16)(acc[mt][nt][2] * s);
        o[3] = (__bf16)(acc[mt][nt][3] * s);
        __bf16* op = (__bf16*)Cout + (size_t)which * (BATCH * SEQ * (size_t)D_MODEL) +
                     ((size_t)(b * NH + h) * SEQ + nn) * HD + d;
        *(bf16x4*)op = o;
      } else {   // EPI 1: V transposed, natural orientation
        int gm0 = tm + wr * 64 + mt * 16 + quad * 4;   // token base
        int gn  = tn + wc * 64 + nt * 16 + l16;        // feature 0..1023
        int b = gm0 >> 11, nn0 = gm0 & 2047, h = gn >> 6, d = gn & 63;
        bf16x4 o;
        o[0] = (__bf16)acc[mt][nt][0];
        o[1] = (__bf16)acc[mt][nt][1];
        o[2] = (__bf16)acc[mt][nt][2];
        o[3] = (__bf16)acc[mt][nt][3];
        __bf16* op = (__bf16*)Cout + ((size_t)(b * NH + h) * HD + d) * SEQ + nn0;
        *(bf16x4*)op = o;
      }
    }
}

// ---------------- causal flash attention ----------------
// grid 1024 (1-D, XCD-swizzled), block 256 (4 waves) -> 4 blocks/CU.
// Block handles q-tile pair (t, 31-t) of 64 rows each; wave w owns 16 rows
// tile*64+w*16 of BOTH tiles. id = (bh&7) + 8*(t + 16*(bh>>3)) puts all 16
// blocks of a bh on one XCD (id%8 round-robin) -> K/V re-reads hit that L2.
// K: LDS-staged (shared by all 4 waves), double-buffered. V: direct global
// b64 loads in A-fragment layout (no LDS round-trip). S^T = mfma(K, Q);
// P stays in registers; PV operand-swapped (lane holds 4 consecutive d per
// q -> bf16x4 ctx stores); row-sums on the MFMA pipe via ones-vector.
// NOTE: __launch_bounds__ 2nd arg = min WORKGROUPS/CU on this compiler
// (R6 evidence: (512,4) -> 64 VGPRs -> spill). (256,4) -> 128 VGPR cap.
__global__ __launch_bounds__(256, 4) void attn(const __bf16* __restrict__ Q,
                                               const __bf16* __restrict__ K,
                                               const __bf16* __restrict__ Vt,
                                               __bf16* __restrict__ ctx) {
  const int tid = threadIdx.x;
  const int lane = tid & 63, w = tid >> 6;
  const int quad = lane >> 4, l16 = lane & 15;
  const int id = blockIdx.x;
  const int t = (id >> 3) & 15;               // pair index 0..15
  const int bh = (id & 7) | ((id >> 7) << 3); // same bh -> same id%8 (XCD)
  const int tile0 = t, tile1 = 31 - t;
  const __bf16* qb = Q + (size_t)bh * SEQ * HD;
  const __bf16* kb = K + (size_t)bh * SEQ * HD;
  const __bf16* vb = Vt + (size_t)bh * HD * SEQ;

  __shared__ __bf16 KsAll[2 * 4096];   // [buf][half*2048 + key*32 + d]

  const int qmin[2] = {tile0 * 64 + w * 16, tile1 * 64 + w * 16};

  // Q fragments (B-operand, scale pre-folded), both phases
  bf16x8 aq[2][2];
#pragma unroll
  for (int p = 0; p < 2; ++p)
#pragma unroll
    for (int kk = 0; kk < 2; ++kk)
      aq[p][kk] = *(const bf16x8*)(qb + (size_t)(qmin[p] + l16) * HD +
                                   kk * 32 + quad * 8);

  f32x4 acc[2][4] = {};    // [phase][cd]: O[q=l16][d=cd*16+quad*4+i]
  f32x4 accs[2] = {};      // [phase]: rowsum, rows q=quad*4+i (ones-MFMA)

  const short4_t ones = {0x3F80, 0x3F80, 0x3F80, 0x3F80};   // bf16 1.0 x4

  // K staging: 8 KB tile = 512 x 16B units; 256 threads x 2 units
  const int u0 = tid, u1 = tid + 256;
  const int kOffG0 = ((u0 >> 2) & 63) * HD + (u0 >> 8) * 32 + (u0 & 3) * 8;
  const int kOffG1 = ((u1 >> 2) & 63) * HD + (u1 >> 8) * 32 + (u1 & 3) * 8;

  auto stage = [&](int k0s, int bufsel) {
    __bf16* Kb = KsAll + bufsel * 4096;
    gld_lds16(kb + (size_t)k0s * HD + kOffG0, Kb + u0 * 8);
    gld_lds16(kb + (size_t)k0s * HD + kOffG1, Kb + u1 * 8);
  };

  const int nIter = tile1 + 1;
  stage(0, 0);

  for (int it = 0; it < nIter; ++it) {
    __syncthreads();   // buf[it&1] staged; all waves done with buf[(it+1)&1]
    if (it + 1 < nIter) stage((it + 1) * 64, (it + 1) & 1);

    const int k0 = it * 64;
    const __bf16* Kb = KsAll + (it & 1) * 4096;

    bf16x8 bk[4][2];          // A-operand K frags: rows = keys
#pragma unroll
    for (int kt = 0; kt < 4; ++kt)
#pragma unroll
      for (int kk = 0; kk < 2; ++kk)
        bk[kt][kk] = *(const bf16x8*)&Kb[kk * 2048 + (kt * 16 + l16) * 32 + quad * 8];

    // V A-frags direct from global (L1/L2-served, XCD-local):
    // vf[kt][cd] = V[k=k0+kt*16+quad*4..+3][d=cd*16+l16]
    short4_t vf[4][4];
#pragma unroll
    for (int kt = 0; kt < 4; ++kt)
#pragma unroll
      for (int cd = 0; cd < 4; ++cd)
        vf[kt][cd] = *(const short4_t*)(vb + (size_t)(cd * 16 + l16) * SEQ +
                                        k0 + kt * 16 + quad * 4);

#pragma unroll
    for (int p = 0; p < 2; ++p) {
      if (k0 > qmin[p] + 15) continue;   // p==1 is always active
      // S^T[k][q]: rows k = k0+kt*16+quad*4+i, col q = qmin[p]+l16
      f32x4 St[4] = {};
#pragma unroll
      for (int kt = 0; kt < 4; ++kt) {
        St[kt] = __builtin_amdgcn_mfma_f32_16x16x32_bf16(
            bk[kt][0], aq[p][0], St[kt], 0, 0, 0);
        St[kt] = __builtin_amdgcn_mfma_f32_16x16x32_bf16(
            bk[kt][1], aq[p][1], St[kt], 0, 0, 0);
      }
      const bool full = (k0 + 63 <= qmin[p]);
#pragma unroll
      for (int kt = 0; kt < 4; ++kt) {
        float e0 = __builtin_amdgcn_exp2f(St[kt][0]);
        float e1 = __builtin_amdgcn_exp2f(St[kt][1]);
        float e2 = __builtin_amdgcn_exp2f(St[kt][2]);
        float e3 = __builtin_amdgcn_exp2f(St[kt][3]);
        if (!full) {
          int kg = k0 + kt * 16 + quad * 4;
          int qg = qmin[p] + l16;
          if (kg + 0 > qg) e0 = 0.f;
          if (kg + 1 > qg) e1 = 0.f;
          if (kg + 2 > qg) e2 = 0.f;
          if (kg + 3 > qg) e3 = 0.f;
        }
        short4_t ap;   // P as B-operand: B[k=quad*4+j][n=l16=q]
        ap[0] = __builtin_bit_cast(short, (__bf16)e0);
        ap[1] = __builtin_bit_cast(short, (__bf16)e1);
        ap[2] = __builtin_bit_cast(short, (__bf16)e2);
        ap[3] = __builtin_bit_cast(short, (__bf16)e3);
        // rowsum on MFMA pipe (ap as A-op: m=l16=q; C rows q=quad*4+i)
        accs[p] = __builtin_amdgcn_mfma_f32_16x16x16bf16_1k(
            ap, ones, accs[p], 0, 0, 0);
        // PV swapped: C[d=quad*4+i][q=l16]
#pragma unroll
        for (int cd = 0; cd < 4; ++cd)
          acc[p][cd] = __builtin_amdgcn_mfma_f32_16x16x16bf16_1k(
              vf[kt][cd], ap, acc[p][cd], 0, 0, 0);
      }
    }
  }

  const int bb = bh >> 4, hh = bh & 15;
#pragma unroll
  for (int p = 0; p < 2; ++p) {
    // accs[p][i] holds rowsum for q = quad*4+i; this lane needs q = l16.
    float sv[4];
#pragma unroll
    for (int i = 0; i < 4; ++i)
      sv[i] = __shfl(accs[p][i], (l16 >> 2) * 16);
    float s01 = (l16 & 1) ? sv[1] : sv[0];
    float s23 = (l16 & 1) ? sv[3] : sv[2];
    float rinv = 1.0f / ((l16 & 2) ? s23 : s01);

    const int q = qmin[p] + l16;
    __bf16* orow = ctx + ((size_t)(bb * SEQ + q)) * D_MODEL + hh * HD;
#pragma unroll
    for (int cd = 0; cd < 4; ++cd) {
      bf16x4 o;
      o[0] = (__bf16)(acc[p][cd][0] * rinv);
      o[1] = (__bf16)(acc[p][cd][1] * rinv);
      o[2] = (__bf16)(acc[p][cd][2] * rinv);
      o[3] = (__bf16)(acc[p][cd][3] * rinv);
      *(bf16x4*)(orow + cd * 16 + quad * 4) = o;
    }
  }
}

extern "C" void kernel_launch(void* const* d_in, const int* in_sizes, int n_in,
                              void* d_out, int out_size, void* d_ws, size_t ws_size,
                              hipStream_t stream) {
  const float* x  = (const float*)d_in[0];
  const float* Wq = (const float*)d_in[1];
  const float* Wk = (const float*)d_in[2];
  const float* Wv = (const float*)d_in[3];
  const float* Wo = (const float*)d_in[4];
  const float* bo = (const float*)d_in[5];
  float* out = (float*)d_out;
  char* ws = (char*)d_ws;
  const size_t MB = 1024 * 1024;
  __bf16* xb   = (__bf16*)(ws);             // 16 MB; reused as ctx after attn
  __bf16* Wqkv = (__bf16*)(ws + 16 * MB);   // 6 MB: Wqt|Wkt|Wvt contiguous
  __bf16* Wot  = (__bf16*)(ws + 22 * MB);   // 2 MB
  __bf16* Qh   = (__bf16*)(ws + 24 * MB);   // 16 MB [b,h,n,d], pre-scaled
  __bf16* Kh   = (__bf16*)(ws + 40 * MB);   // 16 MB [b,h,n,d]
  __bf16* Vth  = (__bf16*)(ws + 56 * MB);   // 16 MB [b,h,d,n]
  __bf16* ctx  = xb;                        // alias: xb dead after QKV GEMM

  cvt_x<<<MROWS * D_MODEL / (256 * 4), 256, 0, stream>>>(x, xb);
  dim3 tb(32, 8);
  cvt_wt<<<dim3(32, 32), tb, 0, stream>>>(Wq, Wqkv);
  cvt_wt<<<dim3(32, 32), tb, 0, stream>>>(Wk, Wqkv + 1024 * 1024);
  cvt_wt<<<dim3(32, 32), tb, 0, stream>>>(Wv, Wqkv + 2 * 1024 * 1024);
  cvt_wt<<<dim3(32, 32), tb, 0, stream>>>(Wo, Wot);

  // QK projection (swapped-operand epilogue), then V projection (natural)
  gemm_bt<0><<<dim3(16, 64), 256, 0, stream>>>(xb, Wqkv, nullptr, Qh);
  gemm_bt<1><<<dim3(8, 64), 256, 0, stream>>>(xb, Wqkv + 2 * 1024 * 1024, nullptr, Vth);

  attn<<<1024, 256, 0, stream>>>(Qh, Kh, Vth, ctx);

  gemm_bt<2><<<dim3(8, 64), 256, 0, stream>>>(ctx, Wot, bo, out);
}

// Round 8
// 442.366 us; speedup vs baseline: 1.3217x; 1.3217x over previous
//
#include <hip/hip_runtime.h>
#include <hip/hip_bf16.h>
#include <math.h>

typedef __attribute__((ext_vector_type(8))) __bf16 bf16x8;
typedef __attribute__((ext_vector_type(4))) __bf16 bf16x4;
typedef __attribute__((ext_vector_type(4))) float f32x4;
typedef __attribute__((ext_vector_type(4))) short short4_t;

#define D_MODEL 1024
#define SEQ     2048
#define BATCH   4
#define NH      16
#define HD      64
#define MROWS   (BATCH * SEQ)   // 8192

// 0.125 (1/sqrt(64)) * log2(e): folded into Q at the QKV-GEMM epilogue
#define SCALE_LOG2E 0.18033688011112042f

__device__ __forceinline__ void gld_lds16(const __bf16* g, __bf16* l) {
  __builtin_amdgcn_global_load_lds(
      (const __attribute__((address_space(1))) void*)g,
      (__attribute__((address_space(3))) void*)l, 16, 0, 0);
}

// ---------------- convert x: fp32 -> bf16, vectorized ----------------
__global__ __launch_bounds__(256) void cvt_x(const float* __restrict__ in,
                                             __bf16* __restrict__ out) {
  int i = (blockIdx.x * 256 + threadIdx.x) * 4;
  float4 f = *(const float4*)(in + i);
  bf16x4 o;
  o.x = (__bf16)f.x; o.y = (__bf16)f.y; o.z = (__bf16)f.z; o.w = (__bf16)f.w;
  *(bf16x4*)(out + i) = o;
}

// ------- convert + transpose weight: fp32 [K][N] -> bf16 [N][K] -------
__global__ __launch_bounds__(256) void cvt_wt(const float* __restrict__ W,
                                              __bf16* __restrict__ Wt) {
  __shared__ __bf16 t[32][33];
  int tx = threadIdx.x, ty = threadIdx.y;   // block (32,8)
  int n0 = blockIdx.x * 32, k0 = blockIdx.y * 32;
#pragma unroll
  for (int j = 0; j < 32; j += 8)
    t[ty + j][tx] = (__bf16)W[(size_t)(k0 + ty + j) * D_MODEL + n0 + tx];
  __syncthreads();
#pragma unroll
  for (int j = 0; j < 32; j += 8)
    Wt[(size_t)(n0 + ty + j) * D_MODEL + k0 + tx] = t[tx][ty + j];
}

// ---------------- GEMM: C[M,N] = A[M,K] @ Bt[N,K]^T  (bf16, m97 structure)
// Operand-swap trick: passing (Bfrag, Afrag) to MFMA yields C^T tiles, so a
// lane holds 4 CONSECUTIVE minor-dim outputs -> vector stores.
// EPI 0 (SWAP): QK, N=2048. lane: token=l16, d=quad*4+i -> bf16x4 to [b,h,n,d]
// EPI 1 (no swap): V, N=1024. lane: d=l16, token=quad*4+i -> bf16x4 to [b,h,d,n]
// EPI 2 (SWAP): proj, N=1024 fp32. lane: row=l16, col=quad*4+i -> float4+bias
template <int EPI>
__global__ __launch_bounds__(256) void gemm_bt(const __bf16* __restrict__ A,
                                               const __bf16* __restrict__ Bt,
                                               const float* __restrict__ bias,
                                               void* __restrict__ Cout) {
  constexpr int Kd = 1024;
  constexpr bool SWAP = (EPI != 1);
  __shared__ __bf16 As[128 * 32];
  __shared__ __bf16 Bs[128 * 32];
  const int tid = threadIdx.x;
  const int lane = tid & 63;
  const int w = tid >> 6;
  const int quad = lane >> 4, l16 = lane & 15;
  const int wr = w >> 1, wc = w & 1;
  const int tm = blockIdx.y * 128, tn = blockIdx.x * 128;

  f32x4 acc[4][4] = {};

  const int u0 = (w * 2) * 64 + lane;
  const int u1 = u0 + 64;
  const int rA0 = u0 >> 2, kofs0 = (u0 & 3) * 8;
  const int rA1 = u1 >> 2, kofs1 = (u1 & 3) * 8;
  const __bf16* gA0 = A + (size_t)(tm + rA0) * Kd + kofs0;
  const __bf16* gA1 = A + (size_t)(tm + rA1) * Kd + kofs1;
  const __bf16* gB0 = Bt + (size_t)(tn + rA0) * Kd + kofs0;
  const __bf16* gB1 = Bt + (size_t)(tn + rA1) * Kd + kofs1;
  __bf16* lA0 = As + (w * 2 + 0) * 512;
  __bf16* lA1 = As + (w * 2 + 1) * 512;
  __bf16* lB0 = Bs + (w * 2 + 0) * 512;
  __bf16* lB1 = Bs + (w * 2 + 1) * 512;

  for (int k0 = 0; k0 < Kd; k0 += 32) {
    gld_lds16(gA0 + k0, lA0);
    gld_lds16(gA1 + k0, lA1);
    gld_lds16(gB0 + k0, lB0);
    gld_lds16(gB1 + k0, lB1);
    __syncthreads();
    bf16x8 af[4], bfr[4];
#pragma unroll
    for (int t = 0; t < 4; ++t) {
      af[t]  = *(const bf16x8*)&As[(wr * 64 + t * 16 + l16) * 32 + quad * 8];
      bfr[t] = *(const bf16x8*)&Bs[(wc * 64 + t * 16 + l16) * 32 + quad * 8];
    }
#pragma unroll
    for (int mt = 0; mt < 4; ++mt)
#pragma unroll
      for (int nt = 0; nt < 4; ++nt) {
        if constexpr (SWAP)
          acc[mt][nt] = __builtin_amdgcn_mfma_f32_16x16x32_bf16(
              bfr[nt], af[mt], acc[mt][nt], 0, 0, 0);
        else
          acc[mt][nt] = __builtin_amdgcn_mfma_f32_16x16x32_bf16(
              af[mt], bfr[nt], acc[mt][nt], 0, 0, 0);
      }
    __syncthreads();
  }

#pragma unroll
  for (int mt = 0; mt < 4; ++mt)
#pragma unroll
    for (int nt = 0; nt < 4; ++nt) {
      if constexpr (EPI == 2) {
        int gm  = tm + wr * 64 + mt * 16 + l16;        // token
        int gn0 = tn + wc * 64 + nt * 16 + quad * 4;   // col base
        float4 bv = *(const float4*)&bias[gn0];
        float4 o;
        o.x = acc[mt][nt][0] + bv.x;
        o.y = acc[mt][nt][1] + bv.y;
        o.z = acc[mt][nt][2] + bv.z;
        o.w = acc[mt][nt][3] + bv.w;
        *(float4*)&((float*)Cout)[(size_t)gm * 1024 + gn0] = o;
      } else if constexpr (EPI == 0) {
        int gm = tm + wr * 64 + mt * 16 + l16;         // token
        int f0 = tn + wc * 64 + nt * 16 + quad * 4;    // 0..2047 (Q|K)
        int which = f0 >> 10, col = f0 & 1023;
        int b = gm >> 11, nn = gm & 2047, h = col >> 6, d = col & 63;
        float s = (which == 0) ? SCALE_LOG2E : 1.0f;
        bf16x4 o;
        o[0] = (__bf16)(acc[mt][nt][0] * s);
        o[1] = (__bf16)(acc[mt][nt][1] * s);
        o[2] = (__bf16)(acc[mt][nt][2] * s);
        o[3] = (__bf16)(acc[mt][nt][3] * s);
        __bf16* op = (__bf16*)Cout + (size_t)which * (BATCH * SEQ * (size_t)D_MODEL) +
                     ((size_t)(b * NH + h) * SEQ + nn) * HD + d;
        *(bf16x4*)op = o;
      } else {   // EPI 1: V transposed, natural orientation
        int gm0 = tm + wr * 64 + mt * 16 + quad * 4;   // token base
        int gn  = tn + wc * 64 + nt * 16 + l16;        // feature 0..1023
        int b = gm0 >> 11, nn0 = gm0 & 2047, h = gn >> 6, d = gn & 63;
        bf16x4 o;
        o[0] = (__bf16)acc[mt][nt][0];
        o[1] = (__bf16)acc[mt][nt][1];
        o[2] = (__bf16)acc[mt][nt][2];
        o[3] = (__bf16)acc[mt][nt][3];
        __bf16* op = (__bf16*)Cout + ((size_t)(b * NH + h) * HD + d) * SEQ + nn0;
        *(bf16x4*)op = o;
      }
    }
}

// ---------------- causal flash attention ----------------
// grid 1024 (1-D, XCD-swizzled), block 256 (4 waves) -> 4 blocks/CU.
// Block handles q-tile pair (t, 31-t) of 64 rows each; wave w owns 16 rows
// tile*64+w*16 of BOTH tiles. id = (bh&7) + 8*(t + 16*(bh>>3)) puts all 16
// blocks of a bh on one XCD (id%8 round-robin) -> K/V re-reads hit that L2.
// K: LDS-staged (shared by all 4 waves), double-buffered. V: direct global
// b64 loads in A-fragment layout (no LDS round-trip). S^T = mfma(K, Q);
// P stays in registers; PV operand-swapped (lane holds 4 consecutive d per
// q -> bf16x4 ctx stores); row-sums on the MFMA pipe via ones-vector.
// WARNING: do NOT pass a 2nd __launch_bounds__ arg here. R6 (512,4) and
// R7 (256,4) both produced a 64-arch-VGPR cap (budget 512/arg split ~half
// arch/half acc with MFMA) -> 370 MB of scratch spill traffic, 3-5x
// slowdown. Bare (256) compiled R5's bigger kernel to 124 VGPRs, no spill.
__global__ __launch_bounds__(256) void attn(const __bf16* __restrict__ Q,
                                            const __bf16* __restrict__ K,
                                            const __bf16* __restrict__ Vt,
                                            __bf16* __restrict__ ctx) {
  const int tid = threadIdx.x;
  const int lane = tid & 63, w = tid >> 6;
  const int quad = lane >> 4, l16 = lane & 15;
  const int id = blockIdx.x;
  const int t = (id >> 3) & 15;               // pair index 0..15
  const int bh = (id & 7) | ((id >> 7) << 3); // same bh -> same id%8 (XCD)
  const int tile0 = t, tile1 = 31 - t;
  const __bf16* qb = Q + (size_t)bh * SEQ * HD;
  const __bf16* kb = K + (size_t)bh * SEQ * HD;
  const __bf16* vb = Vt + (size_t)bh * HD * SEQ;

  __shared__ __bf16 KsAll[2 * 4096];   // [buf][half*2048 + key*32 + d]

  const int qmin[2] = {tile0 * 64 + w * 16, tile1 * 64 + w * 16};

  // Q fragments (B-operand, scale pre-folded), both phases
  bf16x8 aq[2][2];
#pragma unroll
  for (int p = 0; p < 2; ++p)
#pragma unroll
    for (int kk = 0; kk < 2; ++kk)
      aq[p][kk] = *(const bf16x8*)(qb + (size_t)(qmin[p] + l16) * HD +
                                   kk * 32 + quad * 8);

  f32x4 acc[2][4] = {};    // [phase][cd]: O[q=l16][d=cd*16+quad*4+i]
  f32x4 accs[2] = {};      // [phase]: rowsum, rows q=quad*4+i (ones-MFMA)

  const short4_t ones = {0x3F80, 0x3F80, 0x3F80, 0x3F80};   // bf16 1.0 x4

  // K staging: 8 KB tile = 512 x 16B units; 256 threads x 2 units
  const int u0 = tid, u1 = tid + 256;
  const int kOffG0 = ((u0 >> 2) & 63) * HD + (u0 >> 8) * 32 + (u0 & 3) * 8;
  const int kOffG1 = ((u1 >> 2) & 63) * HD + (u1 >> 8) * 32 + (u1 & 3) * 8;

  auto stage = [&](int k0s, int bufsel) {
    __bf16* Kb = KsAll + bufsel * 4096;
    gld_lds16(kb + (size_t)k0s * HD + kOffG0, Kb + u0 * 8);
    gld_lds16(kb + (size_t)k0s * HD + kOffG1, Kb + u1 * 8);
  };

  const int nIter = tile1 + 1;
  stage(0, 0);

  for (int it = 0; it < nIter; ++it) {
    __syncthreads();   // buf[it&1] staged; all waves done with buf[(it+1)&1]
    if (it + 1 < nIter) stage((it + 1) * 64, (it + 1) & 1);

    const int k0 = it * 64;
    const __bf16* Kb = KsAll + (it & 1) * 4096;

    bf16x8 bk[4][2];          // A-operand K frags: rows = keys
#pragma unroll
    for (int kt = 0; kt < 4; ++kt)
#pragma unroll
      for (int kk = 0; kk < 2; ++kk)
        bk[kt][kk] = *(const bf16x8*)&Kb[kk * 2048 + (kt * 16 + l16) * 32 + quad * 8];

    // V A-frags direct from global (L1/L2-served, XCD-local):
    // vf[kt][cd] = V[k=k0+kt*16+quad*4..+3][d=cd*16+l16]
    short4_t vf[4][4];
#pragma unroll
    for (int kt = 0; kt < 4; ++kt)
#pragma unroll
      for (int cd = 0; cd < 4; ++cd)
        vf[kt][cd] = *(const short4_t*)(vb + (size_t)(cd * 16 + l16) * SEQ +
                                        k0 + kt * 16 + quad * 4);

#pragma unroll
    for (int p = 0; p < 2; ++p) {
      if (k0 > qmin[p] + 15) continue;   // p==1 is always active
      // S^T[k][q]: rows k = k0+kt*16+quad*4+i, col q = qmin[p]+l16
      f32x4 St[4] = {};
#pragma unroll
      for (int kt = 0; kt < 4; ++kt) {
        St[kt] = __builtin_amdgcn_mfma_f32_16x16x32_bf16(
            bk[kt][0], aq[p][0], St[kt], 0, 0, 0);
        St[kt] = __builtin_amdgcn_mfma_f32_16x16x32_bf16(
            bk[kt][1], aq[p][1], St[kt], 0, 0, 0);
      }
      const bool full = (k0 + 63 <= qmin[p]);
#pragma unroll
      for (int kt = 0; kt < 4; ++kt) {
        float e0 = __builtin_amdgcn_exp2f(St[kt][0]);
        float e1 = __builtin_amdgcn_exp2f(St[kt][1]);
        float e2 = __builtin_amdgcn_exp2f(St[kt][2]);
        float e3 = __builtin_amdgcn_exp2f(St[kt][3]);
        if (!full) {
          int kg = k0 + kt * 16 + quad * 4;
          int qg = qmin[p] + l16;
          if (kg + 0 > qg) e0 = 0.f;
          if (kg + 1 > qg) e1 = 0.f;
          if (kg + 2 > qg) e2 = 0.f;
          if (kg + 3 > qg) e3 = 0.f;
        }
        short4_t ap;   // P as B-operand: B[k=quad*4+j][n=l16=q]
        ap[0] = __builtin_bit_cast(short, (__bf16)e0);
        ap[1] = __builtin_bit_cast(short, (__bf16)e1);
        ap[2] = __builtin_bit_cast(short, (__bf16)e2);
        ap[3] = __builtin_bit_cast(short, (__bf16)e3);
        // rowsum on MFMA pipe (ap as A-op: m=l16=q; C rows q=quad*4+i)
        accs[p] = __builtin_amdgcn_mfma_f32_16x16x16bf16_1k(
            ap, ones, accs[p], 0, 0, 0);
        // PV swapped: C[d=quad*4+i][q=l16]
#pragma unroll
        for (int cd = 0; cd < 4; ++cd)
          acc[p][cd] = __builtin_amdgcn_mfma_f32_16x16x16bf16_1k(
              vf[kt][cd], ap, acc[p][cd], 0, 0, 0);
      }
    }
  }

  const int bb = bh >> 4, hh = bh & 15;
#pragma unroll
  for (int p = 0; p < 2; ++p) {
    // accs[p][i] holds rowsum for q = quad*4+i; this lane needs q = l16.
    float sv[4];
#pragma unroll
    for (int i = 0; i < 4; ++i)
      sv[i] = __shfl(accs[p][i], (l16 >> 2) * 16);
    float s01 = (l16 & 1) ? sv[1] : sv[0];
    float s23 = (l16 & 1) ? sv[3] : sv[2];
    float rinv = 1.0f / ((l16 & 2) ? s23 : s01);

    const int q = qmin[p] + l16;
    __bf16* orow = ctx + ((size_t)(bb * SEQ + q)) * D_MODEL + hh * HD;
#pragma unroll
    for (int cd = 0; cd < 4; ++cd) {
      bf16x4 o;
      o[0] = (__bf16)(acc[p][cd][0] * rinv);
      o[1] = (__bf16)(acc[p][cd][1] * rinv);
      o[2] = (__bf16)(acc[p][cd][2] * rinv);
      o[3] = (__bf16)(acc[p][cd][3] * rinv);
      *(bf16x4*)(orow + cd * 16 + quad * 4) = o;
    }
  }
}

extern "C" void kernel_launch(void* const* d_in, const int* in_sizes, int n_in,
                              void* d_out, int out_size, void* d_ws, size_t ws_size,
                              hipStream_t stream) {
  const float* x  = (const float*)d_in[0];
  const float* Wq = (const float*)d_in[1];
  const float* Wk = (const float*)d_in[2];
  const float* Wv = (const float*)d_in[3];
  const float* Wo = (const float*)d_in[4];
  const float* bo = (const float*)d_in[5];
  float* out = (float*)d_out;
  char* ws = (char*)d_ws;
  const size_t MB = 1024 * 1024;
  __bf16* xb   = (__bf16*)(ws);             // 16 MB; reused as ctx after attn
  __bf16* Wqkv = (__bf16*)(ws + 16 * MB);   // 6 MB: Wqt|Wkt|Wvt contiguous
  __bf16* Wot  = (__bf16*)(ws + 22 * MB);   // 2 MB
  __bf16* Qh   = (__bf16*)(ws + 24 * MB);   // 16 MB [b,h,n,d], pre-scaled
  __bf16* Kh   = (__bf16*)(ws + 40 * MB);   // 16 MB [b,h,n,d]
  __bf16* Vth  = (__bf16*)(ws + 56 * MB);   // 16 MB [b,h,d,n]
  __bf16* ctx  = xb;                        // alias: xb dead after QKV GEMM

  cvt_x<<<MROWS * D_MODEL / (256 * 4), 256, 0, stream>>>(x, xb);
  dim3 tb(32, 8);
  cvt_wt<<<dim3(32, 32), tb, 0, stream>>>(Wq, Wqkv);
  cvt_wt<<<dim3(32, 32), tb, 0, stream>>>(Wk, Wqkv + 1024 * 1024);
  cvt_wt<<<dim3(32, 32), tb, 0, stream>>>(Wv, Wqkv + 2 * 1024 * 1024);
  cvt_wt<<<dim3(32, 32), tb, 0, stream>>>(Wo, Wot);

  // QK projection (swapped-operand epilogue), then V projection (natural)
  gemm_bt<0><<<dim3(16, 64), 256, 0, stream>>>(xb, Wqkv, nullptr, Qh);
  gemm_bt<1><<<dim3(8, 64), 256, 0, stream>>>(xb, Wqkv + 2 * 1024 * 1024, nullptr, Vth);

  attn<<<1024, 256, 0, stream>>>(Qh, Kh, Vth, ctx);

  gemm_bt<2><<<dim3(8, 64), 256, 0, stream>>>(ctx, Wot, bo, out);
}

// Round 9
// 293.156 us; speedup vs baseline: 1.9945x; 1.5090x over previous
//
#include <hip/hip_runtime.h>
#include <hip/hip_bf16.h>
#include <math.h>

typedef __attribute__((ext_vector_type(8))) __bf16 bf16x8;
typedef __attribute__((ext_vector_type(4))) __bf16 bf16x4;
typedef __attribute__((ext_vector_type(4))) float f32x4;
typedef __attribute__((ext_vector_type(4))) short short4_t;

#define D_MODEL 1024
#define SEQ     2048
#define BATCH   4
#define NH      16
#define HD      64
#define MROWS   (BATCH * SEQ)   // 8192

// 0.125 (1/sqrt(64)) * log2(e): folded into Q at the QKV-GEMM epilogue
#define SCALE_LOG2E 0.18033688011112042f

__device__ __forceinline__ void gld_lds16(const __bf16* g, __bf16* l) {
  __builtin_amdgcn_global_load_lds(
      (const __attribute__((address_space(1))) void*)g,
      (__attribute__((address_space(3))) void*)l, 16, 0, 0);
}

// ---------------- convert x: fp32 -> bf16, vectorized ----------------
__global__ __launch_bounds__(256) void cvt_x(const float* __restrict__ in,
                                             __bf16* __restrict__ out) {
  int i = (blockIdx.x * 256 + threadIdx.x) * 4;
  float4 f = *(const float4*)(in + i);
  bf16x4 o;
  o.x = (__bf16)f.x; o.y = (__bf16)f.y; o.z = (__bf16)f.z; o.w = (__bf16)f.w;
  *(bf16x4*)(out + i) = o;
}

// ------- convert + transpose weight: fp32 [K][N] -> bf16 [N][K] -------
__global__ __launch_bounds__(256) void cvt_wt(const float* __restrict__ W,
                                              __bf16* __restrict__ Wt) {
  __shared__ __bf16 t[32][33];
  int tx = threadIdx.x, ty = threadIdx.y;   // block (32,8)
  int n0 = blockIdx.x * 32, k0 = blockIdx.y * 32;
#pragma unroll
  for (int j = 0; j < 32; j += 8)
    t[ty + j][tx] = (__bf16)W[(size_t)(k0 + ty + j) * D_MODEL + n0 + tx];
  __syncthreads();
#pragma unroll
  for (int j = 0; j < 32; j += 8)
    Wt[(size_t)(n0 + ty + j) * D_MODEL + k0 + tx] = t[tx][ty + j];
}

// ---------------- GEMM: C[M,N] = A[M,K] @ Bt[N,K]^T  (bf16, m97 structure)
// Operand-swap trick: passing (Bfrag, Afrag) to MFMA yields C^T tiles, so a
// lane holds 4 CONSECUTIVE minor-dim outputs -> vector stores.
// EPI 0 (SWAP): QK, N=2048. lane: token=l16, d=quad*4+i -> bf16x4 to [b,h,n,d]
// EPI 1 (no swap): V, N=1024. lane: d=l16, token=quad*4+i -> bf16x4 to [b,h,d,n]
// EPI 2 (SWAP): proj, N=1024 fp32. lane: row=l16, col=quad*4+i -> float4+bias
template <int EPI>
__global__ __launch_bounds__(256) void gemm_bt(const __bf16* __restrict__ A,
                                               const __bf16* __restrict__ Bt,
                                               const float* __restrict__ bias,
                                               void* __restrict__ Cout) {
  constexpr int Kd = 1024;
  constexpr bool SWAP = (EPI != 1);
  __shared__ __bf16 As[128 * 32];
  __shared__ __bf16 Bs[128 * 32];
  const int tid = threadIdx.x;
  const int lane = tid & 63;
  const int w = tid >> 6;
  const int quad = lane >> 4, l16 = lane & 15;
  const int wr = w >> 1, wc = w & 1;
  const int tm = blockIdx.y * 128, tn = blockIdx.x * 128;

  f32x4 acc[4][4] = {};

  const int u0 = (w * 2) * 64 + lane;
  const int u1 = u0 + 64;
  const int rA0 = u0 >> 2, kofs0 = (u0 & 3) * 8;
  const int rA1 = u1 >> 2, kofs1 = (u1 & 3) * 8;
  const __bf16* gA0 = A + (size_t)(tm + rA0) * Kd + kofs0;
  const __bf16* gA1 = A + (size_t)(tm + rA1) * Kd + kofs1;
  const __bf16* gB0 = Bt + (size_t)(tn + rA0) * Kd + kofs0;
  const __bf16* gB1 = Bt + (size_t)(tn + rA1) * Kd + kofs1;
  __bf16* lA0 = As + (w * 2 + 0) * 512;
  __bf16* lA1 = As + (w * 2 + 1) * 512;
  __bf16* lB0 = Bs + (w * 2 + 0) * 512;
  __bf16* lB1 = Bs + (w * 2 + 1) * 512;

  for (int k0 = 0; k0 < Kd; k0 += 32) {
    gld_lds16(gA0 + k0, lA0);
    gld_lds16(gA1 + k0, lA1);
    gld_lds16(gB0 + k0, lB0);
    gld_lds16(gB1 + k0, lB1);
    __syncthreads();
    bf16x8 af[4], bfr[4];
#pragma unroll
    for (int t = 0; t < 4; ++t) {
      af[t]  = *(const bf16x8*)&As[(wr * 64 + t * 16 + l16) * 32 + quad * 8];
      bfr[t] = *(const bf16x8*)&Bs[(wc * 64 + t * 16 + l16) * 32 + quad * 8];
    }
#pragma unroll
    for (int mt = 0; mt < 4; ++mt)
#pragma unroll
      for (int nt = 0; nt < 4; ++nt) {
        if constexpr (SWAP)
          acc[mt][nt] = __builtin_amdgcn_mfma_f32_16x16x32_bf16(
              bfr[nt], af[mt], acc[mt][nt], 0, 0, 0);
        else
          acc[mt][nt] = __builtin_amdgcn_mfma_f32_16x16x32_bf16(
              af[mt], bfr[nt], acc[mt][nt], 0, 0, 0);
      }
    __syncthreads();
  }

#pragma unroll
  for (int mt = 0; mt < 4; ++mt)
#pragma unroll
    for (int nt = 0; nt < 4; ++nt) {
      if constexpr (EPI == 2) {
        int gm  = tm + wr * 64 + mt * 16 + l16;        // token
        int gn0 = tn + wc * 64 + nt * 16 + quad * 4;   // col base
        float4 bv = *(const float4*)&bias[gn0];
        float4 o;
        o.x = acc[mt][nt][0] + bv.x;
        o.y = acc[mt][nt][1] + bv.y;
        o.z = acc[mt][nt][2] + bv.z;
        o.w = acc[mt][nt][3] + bv.w;
        *(float4*)&((float*)Cout)[(size_t)gm * 1024 + gn0] = o;
      } else if constexpr (EPI == 0) {
        int gm = tm + wr * 64 + mt * 16 + l16;         // token
        int f0 = tn + wc * 64 + nt * 16 + quad * 4;    // 0..2047 (Q|K)
        int which = f0 >> 10, col = f0 & 1023;
        int b = gm >> 11, nn = gm & 2047, h = col >> 6, d = col & 63;
        float s = (which == 0) ? SCALE_LOG2E : 1.0f;
        bf16x4 o;
        o[0] = (__bf16)(acc[mt][nt][0] * s);
        o[1] = (__bf16)(acc[mt][nt][1] * s);
        o[2] = (__bf16)(acc[mt][nt][2] * s);
        o[3] = (__bf16)(acc[mt][nt][3] * s);
        __bf16* op = (__bf16*)Cout + (size_t)which * (BATCH * SEQ * (size_t)D_MODEL) +
                     ((size_t)(b * NH + h) * SEQ + nn) * HD + d;
        *(bf16x4*)op = o;
      } else {   // EPI 1: V transposed, natural orientation
        int gm0 = tm + wr * 64 + mt * 16 + quad * 4;   // token base
        int gn  = tn + wc * 64 + nt * 16 + l16;        // feature 0..1023
        int b = gm0 >> 11, nn0 = gm0 & 2047, h = gn >> 6, d = gn & 63;
        bf16x4 o;
        o[0] = (__bf16)acc[mt][nt][0];
        o[1] = (__bf16)acc[mt][nt][1];
        o[2] = (__bf16)acc[mt][nt][2];
        o[3] = (__bf16)acc[mt][nt][3];
        __bf16* op = (__bf16*)Cout + ((size_t)(b * NH + h) * HD + d) * SEQ + nn0;
        *(bf16x4*)op = o;
      }
    }
}

// ---------------- causal flash attention ----------------
// grid 1024 (1-D, XCD-swizzled), block 256 (4 waves) -> 4 blocks/CU.
// Block handles q-tile pair (t, 31-t) of 64 rows each; wave w owns 16 rows
// tile*64+w*16 of BOTH tiles. id = (bh&7) + 8*(t + 16*(bh>>3)) puts all 16
// blocks of a bh on one XCD (id%8 round-robin) -> K/V re-reads hit that L2.
// K AND V double-buffered in LDS (V with XOR swizzle so b64 frag reads are
// bank-conflict-free). R8 evidence: direct-global V frags (4KB row stride)
// alias to ONE L1 set -> every read is an L2-latency miss -> 3.4x slowdown.
// S^T = mfma(K, Q); P stays in registers; PV operand-swapped (lane holds 4
// consecutive d per q -> bf16x4 ctx stores); row-sums on the MFMA pipe.
// WARNING: do NOT pass a 2nd __launch_bounds__ arg. R6 (512,4) / R7 (256,4)
// both produced a 64-arch-VGPR cap (budget split arch/acc with MFMA) ->
// 370 MB scratch spill, 3-5x slowdown. Bare (256) -> no spill.
__global__ __launch_bounds__(256) void attn(const __bf16* __restrict__ Q,
                                            const __bf16* __restrict__ K,
                                            const __bf16* __restrict__ Vt,
                                            __bf16* __restrict__ ctx) {
  const int tid = threadIdx.x;
  const int lane = tid & 63, w = tid >> 6;
  const int quad = lane >> 4, l16 = lane & 15;
  const int id = blockIdx.x;
  const int t = (id >> 3) & 15;               // pair index 0..15
  const int bh = (id & 7) | ((id >> 7) << 3); // same bh -> same id%8 (XCD)
  const int tile0 = t, tile1 = 31 - t;
  const __bf16* qb = Q + (size_t)bh * SEQ * HD;
  const __bf16* kb = K + (size_t)bh * SEQ * HD;
  const __bf16* vb = Vt + (size_t)bh * HD * SEQ;

  __shared__ __bf16 KsAll[2 * 4096];   // [buf][half*2048 + key*32 + d]
  __shared__ __bf16 VsAll[2 * 4096];   // [buf][d*64 + ((k>>3)^(d&7))*8 + (k&7)]

  const int qmin[2] = {tile0 * 64 + w * 16, tile1 * 64 + w * 16};

  // Q fragments (B-operand, scale pre-folded), both phases
  bf16x8 aq[2][2];
#pragma unroll
  for (int p = 0; p < 2; ++p)
#pragma unroll
    for (int kk = 0; kk < 2; ++kk)
      aq[p][kk] = *(const bf16x8*)(qb + (size_t)(qmin[p] + l16) * HD +
                                   kk * 32 + quad * 8);

  f32x4 acc[2][4] = {};    // [phase][cd]: O[q=l16][d=cd*16+quad*4+i]
  f32x4 accs[2] = {};      // [phase]: rowsum, rows q=quad*4+i (ones-MFMA)

  const short4_t ones = {0x3F80, 0x3F80, 0x3F80, 0x3F80};   // bf16 1.0 x4

  // staging: K tile 512 units (16B), V tile 512 units; 256 threads x 2 each
  const int u0 = tid, u1 = tid + 256;
  const int kOffG0 = ((u0 >> 2) & 63) * HD + (u0 >> 8) * 32 + (u0 & 3) * 8;
  const int kOffG1 = ((u1 >> 2) & 63) * HD + (u1 >> 8) * 32 + (u1 & 3) * 8;
  const int vd0 = u0 >> 3, vd1 = u1 >> 3;
  const int vOffG0 = vd0 * SEQ + (((u0 & 7) ^ (vd0 & 7)) * 8);
  const int vOffG1 = vd1 * SEQ + (((u1 & 7) ^ (vd1 & 7)) * 8);

  auto stage = [&](int k0s, int bufsel) {
    __bf16* Kb = KsAll + bufsel * 4096;
    __bf16* Vb = VsAll + bufsel * 4096;
    gld_lds16(kb + (size_t)k0s * HD + kOffG0, Kb + u0 * 8);
    gld_lds16(kb + (size_t)k0s * HD + kOffG1, Kb + u1 * 8);
    gld_lds16(vb + k0s + vOffG0, Vb + u0 * 8);
    gld_lds16(vb + k0s + vOffG1, Vb + u1 * 8);
  };

  const int nIter = tile1 + 1;
  stage(0, 0);

  for (int it = 0; it < nIter; ++it) {
    __syncthreads();   // buf[it&1] staged; all waves done with buf[(it+1)&1]
    if (it + 1 < nIter) stage((it + 1) * 64, (it + 1) & 1);

    const int k0 = it * 64;
    const __bf16* Kb = KsAll + (it & 1) * 4096;
    const __bf16* Vb = VsAll + (it & 1) * 4096;

    bf16x8 bk[4][2];          // A-operand K frags: rows = keys
#pragma unroll
    for (int kt = 0; kt < 4; ++kt)
#pragma unroll
      for (int kk = 0; kk < 2; ++kk)
        bk[kt][kk] = *(const bf16x8*)&Kb[kk * 2048 + (kt * 16 + l16) * 32 + quad * 8];

    // V A-frags from swizzled LDS (bank-conflict-free b64):
    // vf[kt][cd] = V[k=k0+kt*16+quad*4..+3][d=cd*16+l16]
    short4_t vf[4][4];
#pragma unroll
    for (int kt = 0; kt < 4; ++kt)
#pragma unroll
      for (int cd = 0; cd < 4; ++cd)
        vf[kt][cd] = *(const short4_t*)&Vb[(cd * 16 + l16) * 64 +
                                           (((kt * 2 + (quad >> 1)) ^ (l16 & 7)) * 8) +
                                           (quad & 1) * 4];

#pragma unroll
    for (int p = 0; p < 2; ++p) {
      if (k0 > qmin[p] + 15) continue;   // p==1 is always active
      // S^T[k][q]: rows k = k0+kt*16+quad*4+i, col q = qmin[p]+l16
      f32x4 St[4] = {};
#pragma unroll
      for (int kt = 0; kt < 4; ++kt) {
        St[kt] = __builtin_amdgcn_mfma_f32_16x16x32_bf16(
            bk[kt][0], aq[p][0], St[kt], 0, 0, 0);
        St[kt] = __builtin_amdgcn_mfma_f32_16x16x32_bf16(
            bk[kt][1], aq[p][1], St[kt], 0, 0, 0);
      }
      const bool full = (k0 + 63 <= qmin[p]);
#pragma unroll
      for (int kt = 0; kt < 4; ++kt) {
        float e0 = __builtin_amdgcn_exp2f(St[kt][0]);
        float e1 = __builtin_amdgcn_exp2f(St[kt][1]);
        float e2 = __builtin_amdgcn_exp2f(St[kt][2]);
        float e3 = __builtin_amdgcn_exp2f(St[kt][3]);
        if (!full) {
          int kg = k0 + kt * 16 + quad * 4;
          int qg = qmin[p] + l16;
          if (kg + 0 > qg) e0 = 0.f;
          if (kg + 1 > qg) e1 = 0.f;
          if (kg + 2 > qg) e2 = 0.f;
          if (kg + 3 > qg) e3 = 0.f;
        }
        short4_t ap;   // P as B-operand: B[k=quad*4+j][n=l16=q]
        ap[0] = __builtin_bit_cast(short, (__bf16)e0);
        ap[1] = __builtin_bit_cast(short, (__bf16)e1);
        ap[2] = __builtin_bit_cast(short, (__bf16)e2);
        ap[3] = __builtin_bit_cast(short, (__bf16)e3);
        // rowsum on MFMA pipe (ap as A-op: m=l16=q; C rows q=quad*4+i)
        accs[p] = __builtin_amdgcn_mfma_f32_16x16x16bf16_1k(
            ap, ones, accs[p], 0, 0, 0);
        // PV swapped: C[d=quad*4+i][q=l16]
#pragma unroll
        for (int cd = 0; cd < 4; ++cd)
          acc[p][cd] = __builtin_amdgcn_mfma_f32_16x16x16bf16_1k(
              vf[kt][cd], ap, acc[p][cd], 0, 0, 0);
      }
    }
  }

  const int bb = bh >> 4, hh = bh & 15;
#pragma unroll
  for (int p = 0; p < 2; ++p) {
    // accs[p][i] holds rowsum for q = quad*4+i; this lane needs q = l16.
    float sv[4];
#pragma unroll
    for (int i = 0; i < 4; ++i)
      sv[i] = __shfl(accs[p][i], (l16 >> 2) * 16);
    float s01 = (l16 & 1) ? sv[1] : sv[0];
    float s23 = (l16 & 1) ? sv[3] : sv[2];
    float rinv = 1.0f / ((l16 & 2) ? s23 : s01);

    const int q = qmin[p] + l16;
    __bf16* orow = ctx + ((size_t)(bb * SEQ + q)) * D_MODEL + hh * HD;
#pragma unroll
    for (int cd = 0; cd < 4; ++cd) {
      bf16x4 o;
      o[0] = (__bf16)(acc[p][cd][0] * rinv);
      o[1] = (__bf16)(acc[p][cd][1] * rinv);
      o[2] = (__bf16)(acc[p][cd][2] * rinv);
      o[3] = (__bf16)(acc[p][cd][3] * rinv);
      *(bf16x4*)(orow + cd * 16 + quad * 4) = o;
    }
  }
}

extern "C" void kernel_launch(void* const* d_in, const int* in_sizes, int n_in,
                              void* d_out, int out_size, void* d_ws, size_t ws_size,
                              hipStream_t stream) {
  const float* x  = (const float*)d_in[0];
  const float* Wq = (const float*)d_in[1];
  const float* Wk = (const float*)d_in[2];
  const float* Wv = (const float*)d_in[3];
  const float* Wo = (const float*)d_in[4];
  const float* bo = (const float*)d_in[5];
  float* out = (float*)d_out;
  char* ws = (char*)d_ws;
  const size_t MB = 1024 * 1024;
  __bf16* xb   = (__bf16*)(ws);             // 16 MB; reused as ctx after attn
  __bf16* Wqkv = (__bf16*)(ws + 16 * MB);   // 6 MB: Wqt|Wkt|Wvt contiguous
  __bf16* Wot  = (__bf16*)(ws + 22 * MB);   // 2 MB
  __bf16* Qh   = (__bf16*)(ws + 24 * MB);   // 16 MB [b,h,n,d], pre-scaled
  __bf16* Kh   = (__bf16*)(ws + 40 * MB);   // 16 MB [b,h,n,d]
  __bf16* Vth  = (__bf16*)(ws + 56 * MB);   // 16 MB [b,h,d,n]
  __bf16* ctx  = xb;                        // alias: xb dead after QKV GEMM

  cvt_x<<<MROWS * D_MODEL / (256 * 4), 256, 0, stream>>>(x, xb);
  dim3 tb(32, 8);
  cvt_wt<<<dim3(32, 32), tb, 0, stream>>>(Wq, Wqkv);
  cvt_wt<<<dim3(32, 32), tb, 0, stream>>>(Wk, Wqkv + 1024 * 1024);
  cvt_wt<<<dim3(32, 32), tb, 0, stream>>>(Wv, Wqkv + 2 * 1024 * 1024);
  cvt_wt<<<dim3(32, 32), tb, 0, stream>>>(Wo, Wot);

  // QK projection (swapped-operand epilogue), then V projection (natural)
  gemm_bt<0><<<dim3(16, 64), 256, 0, stream>>>(xb, Wqkv, nullptr, Qh);
  gemm_bt<1><<<dim3(8, 64), 256, 0, stream>>>(xb, Wqkv + 2 * 1024 * 1024, nullptr, Vth);

  attn<<<1024, 256, 0, stream>>>(Qh, Kh, Vth, ctx);

  gemm_bt<2><<<dim3(8, 64), 256, 0, stream>>>(ctx, Wot, bo, out);
}